// Round 4
// baseline (399.787 us; speedup 1.0000x reference)
//
#include <hip/hip_runtime.h>

// BertEmbedding + 5-layer GAT on MI355X (gfx950). Round 10 (resubmit —
// round-11 bench hit GPUAcquisitionTimeout, kernel never ran):
//  - Round-9 analysis: all kernels < 60us; critical path = dispatch drains +
//    standalone k_final (146MB stream). k_gemm dispatches run at 7.3 waves/CU
//    (75% of wave slots idle).
//  - k_final's non-CLS rows (32704/32768) depend ONLY on input tables, not
//    the GNN. They now ride as extra blocks inside the layer-0 k_gemm
//    dispatch (complementary: MFMA/L2-bound gemm + HBM-latency-bound rows).
//    Only a 64-row CLS kernel (~4us) remains after the last GAT.
//  - k_final body: 4 rows/wave, all 4 scattered word-gathers hoisted
//    (gather-latency-bound at 2.55 TB/s in round 7), nontemporal stores.
//  - k_gemm layers 1-4: 64-thread 1-wave blocks (1872 blocks, even 7.3/CU;
//    was 468 4-wave blocks -> 212 CUs with 2 blocks, 44 with 1 = tail).
//  - GAT/front/math byte-identical to passing round-9 kernel.

#define DEV __device__ __forceinline__

typedef short s16x8 __attribute__((ext_vector_type(8)));
typedef float f32x4 __attribute__((ext_vector_type(4)));
typedef unsigned short u16x8 __attribute__((ext_vector_type(8)));

DEV float b2f(unsigned int u) { union { unsigned int i; float f; } v; v.i = u << 16; return v.f; }
DEV unsigned short f2b(float f) {
  union { float f; unsigned int i; } v; v.f = f;
  return (unsigned short)((v.i + 0x7fffu + ((v.i >> 16) & 1u)) >> 16);
}
DEV float gelu_exact(float x) { return 0.5f * x * (1.f + erff(x * 0.70710678118654752f)); }

// dual-dtype loads. fF: floats are f32 (else bf16). fI: ints are int64.
DEV float ldf(const void* p, size_t i, int fF) {
  return fF ? ((const float*)p)[i] : b2f(((const unsigned short*)p)[i]);
}
DEV int ldi(const void* p, size_t i, int fI) {
  return fI ? ((const int*)p)[2 * i] : ((const int*)p)[i];
}

// Fragment-linear offset for element [n][d] of a [rows][768] matrix.
DEV size_t frag_off(int n, int d) {
  return ((((size_t)(n >> 4) * 24 + (size_t)(d >> 5)) * 64 +
           (((d >> 3) & 3) << 4) + (n & 15)) << 3) + (d & 7);
}

// ---------------------------------------------------------------------------
// k_front: fused front-end, 1357 blocks (identical to round 9).
// ---------------------------------------------------------------------------
__global__ __launch_bounds__(256) void k_front(const void* __restrict__ src,
                                               const void* __restrict__ sst,
                                               const void* __restrict__ sen,
                                               const void* __restrict__ edge,
                                               const void* __restrict__ word,
                                               const void* __restrict__ pos,
                                               const void* __restrict__ aS,
                                               const void* __restrict__ aD,
                                               const void* __restrict__ Wg,
                                               unsigned short* __restrict__ xh,
                                               unsigned short* __restrict__ xl,
                                               unsigned short* __restrict__ Bh,
                                               unsigned short* __restrict__ Bl,
                                               int* __restrict__ csr_off,
                                               int* __restrict__ csr_src,
                                               int* __restrict__ flags) {
  __shared__ int sflags[2];
  __shared__ float tile[64][65];
  __shared__ float sA[768], sD[768];
  __shared__ int cnt[576], off[577], fill[576];
  int t = threadIdx.x, bid = blockIdx.x;
  if (t < 64) {
    const unsigned short* w16 = (const unsigned short*)word;
    int crazy = 0;
    for (int i = t; i < 512; i += 64) {
      unsigned int e = (w16[i] >> 7) & 0xffu;
      if (e >= 135u || (e >= 1u && e <= 100u)) crazy++;
    }
#pragma unroll
    for (int o = 32; o > 0; o >>= 1) crazy += __shfl_down(crazy, o);
    if (t == 0) {
      sflags[0] = (crazy >= 8) ? 1 : 0;
      sflags[1] = (((const int*)pos)[1] == 0) ? 1 : 0;
    }
  }
  __syncthreads();
  int fF = sflags[0], fI = sflags[1];
  if (bid == 0 && t == 0) { flags[0] = fF; flags[1] = fI; }

  if (bid < 780) {
    int layer = bid / 156, r = bid % 156, kt = r / 13, nt = r % 13;
    int k0 = kt * 64, n0 = nt * 64;
    if (nt < 12) {
#pragma unroll
      for (int i = 0; i < 16; ++i) {
        int e = t + 256 * i, rk = e >> 6, cn = e & 63;
        tile[rk][cn] = ldf(Wg, ((size_t)layer * 768 + k0 + rk) * 768 + n0 + cn, fF);
      }
    } else {
      for (int i = t; i < 768; i += 256) {
        sA[i] = ldf(aS, (size_t)layer * 768 + i, fF);
        sD[i] = ldf(aD, (size_t)layer * 768 + i, fF);
      }
#pragma unroll
      for (int i = 0; i < 16; ++i) {
        int e = t + 256 * i, rk = e >> 6, cn = e & 63;
        if (cn >= 8) tile[rk][cn] = 0.f;
      }
      __syncthreads();
      int wave = t >> 6, lane = t & 63;
      for (int rr = 0; rr < 16; ++rr) {
        int rk = wave * 16 + rr;
        size_t wbase = ((size_t)layer * 768 + k0 + rk) * 768;
        float accS[4] = {0.f, 0.f, 0.f, 0.f}, accD[4] = {0.f, 0.f, 0.f, 0.f};
#pragma unroll
        for (int i = 0; i < 12; ++i) {
          int d = lane + 64 * i;
          float w = ldf(Wg, wbase + d, fF);
          accS[i / 3] += w * sA[d];
          accD[i / 3] += w * sD[d];
        }
#pragma unroll
        for (int h = 0; h < 4; ++h) {
          float sS = accS[h], sDv = accD[h];
#pragma unroll
          for (int o = 32; o > 0; o >>= 1) {
            sS += __shfl_down(sS, o);
            sDv += __shfl_down(sDv, o);
          }
          if (lane == 0) { tile[rk][h] = sS; tile[rk][4 + h] = sDv; }
        }
      }
    }
    __syncthreads();
    size_t lb = (size_t)layer * 79872;
#pragma unroll
    for (int g = 0; g < 2; ++g) {
      int G = t * 2 + g, rn = G & 63, c8 = G >> 6;
      int n = n0 + rn, kb = k0 + c8 * 8;
      u16x8 hv, lv;
#pragma unroll
      for (int j = 0; j < 8; ++j) {
        float v = tile[c8 * 8 + j][rn];
        unsigned short hi = f2b(v);
        hv[j] = hi;
        lv[j] = f2b(v - b2f((unsigned int)hi));
      }
      size_t go = lb + ((size_t)(n >> 4) * 24 + (size_t)(kb >> 5)) * 64 +
                  (((kb >> 3) & 3) << 4) + (n & 15);
      *(u16x8*)(Bh + go * 8) = hv;
      *(u16x8*)(Bl + go * 8) = lv;
    }
  } else if (bid < 1356) {
    int g = bid - 780;
    int b = g / 9, j = g % 9;
    float v[3] = {0.f, 0.f, 0.f};
    if (j == 0) {
      int rr = ldi(src, (size_t)b * 512, fI);
#pragma unroll
      for (int ii = 0; ii < 3; ++ii) v[ii] = ldf(word, (size_t)rr * 768 + t + 256 * ii, fF);
    } else {
      int st = ldi(sst, (size_t)b * 8 + j - 1, fI);
      int en = ldi(sen, (size_t)b * 8 + j - 1, fI);
      for (int s = st; s <= en; ++s) {
        int rr = ldi(src, (size_t)b * 512 + s, fI);
#pragma unroll
        for (int ii = 0; ii < 3; ++ii) v[ii] += ldf(word, (size_t)rr * 768 + t + 256 * ii, fF);
      }
    }
#pragma unroll
    for (int ii = 0; ii < 3; ++ii) {
      int d = t + 256 * ii;
      unsigned short hi = f2b(v[ii]);
      size_t o = frag_off(g, d);
      xh[o] = hi;
      xl[o] = f2b(v[ii] - b2f((unsigned int)hi));
    }
  } else {
    for (int i = t; i < 576; i += 256) cnt[i] = 0;
    __syncthreads();
    for (int e = t; e < 8768; e += 256) {
      int di;
      if (e < 4096) di = ldi(edge, (size_t)4096 + e, fI);
      else if (e < 8192) di = ldi(edge, (size_t)e - 4096, fI);
      else di = e - 8192;
      atomicAdd(&cnt[di], 1);
    }
    __syncthreads();
    if (t == 0) {
      int a = 0;
      for (int i = 0; i < 576; ++i) { off[i] = a; a += cnt[i]; }
      off[576] = a;
    }
    __syncthreads();
    for (int i = t; i < 577; i += 256) csr_off[i] = off[i];
    for (int i = t; i < 576; i += 256) fill[i] = off[i];
    __syncthreads();
    for (int e = t; e < 8768; e += 256) {
      int si, di;
      if (e < 4096)      { si = ldi(edge, (size_t)e, fI); di = ldi(edge, (size_t)4096 + e, fI); }
      else if (e < 8192) { si = ldi(edge, (size_t)e, fI); di = ldi(edge, (size_t)e - 4096, fI); }
      else               { si = e - 8192;                 di = si; }
      int p = atomicAdd(&fill[di], 1);
      csr_src[p] = si;
    }
  }
}

// ---------------------------------------------------------------------------
// GEMM wave body: one 16x16 C-tile, LDS-free, barrier-free, 3 MFMA chains.
// ---------------------------------------------------------------------------
DEV void gemm_wave(int wid, int lane,
                   const unsigned short* __restrict__ xh,
                   const unsigned short* __restrict__ xl,
                   const unsigned short* __restrict__ Bh,
                   const unsigned short* __restrict__ Bl,
                   float* __restrict__ C) {
  int rt = wid / 52, ct = wid % 52;
  const s16x8* Ah = (const s16x8*)xh + (size_t)rt * 1536 + lane;
  const s16x8* Al = (const s16x8*)xl + (size_t)rt * 1536 + lane;
  const s16x8* Bhp = (const s16x8*)Bh + (size_t)ct * 1536 + lane;
  const s16x8* Blp = (const s16x8*)Bl + (size_t)ct * 1536 + lane;
  f32x4 a0 = {0.f, 0.f, 0.f, 0.f}, a1 = a0, a2 = a0;
#pragma unroll 6
  for (int kk = 0; kk < 24; ++kk) {
    s16x8 ah = Ah[kk * 64];
    s16x8 al = Al[kk * 64];
    s16x8 bh = Bhp[kk * 64];
    s16x8 bl = Blp[kk * 64];
    a0 = __builtin_amdgcn_mfma_f32_16x16x32_bf16(ah, bh, a0, 0, 0, 0);
    a1 = __builtin_amdgcn_mfma_f32_16x16x32_bf16(ah, bl, a1, 0, 0, 0);
    a2 = __builtin_amdgcn_mfma_f32_16x16x32_bf16(al, bh, a2, 0, 0, 0);
  }
  int row0 = rt * 16 + (lane >> 4) * 4, col = ct * 16 + (lane & 15);
#pragma unroll
  for (int r = 0; r < 4; ++r)
    C[(size_t)(row0 + r) * 832 + col] = a0[r] + a1[r] + a2[r];
}

// k_gemm (layers 1-4): 1872 one-wave blocks -> even 7.3 waves/CU.
__global__ __launch_bounds__(64) void k_gemm(const unsigned short* __restrict__ xh,
                                             const unsigned short* __restrict__ xl,
                                             const unsigned short* __restrict__ Bh,
                                             const unsigned short* __restrict__ Bl,
                                             float* __restrict__ C) {
  gemm_wave(blockIdx.x, threadIdx.x & 63, xh, xl, Bh, Bl, C);
}

// ---------------------------------------------------------------------------
// final-row helpers (round-9 verified math).
// ---------------------------------------------------------------------------
DEV void final_row_f32(int r, int lane, const f32x4* wsrc,
                       const void* seg, const void* typ, const void* post,
                       const void* segt, const void* typt,
                       const void* gamma, const void* beta, int fI,
                       float* __restrict__ outp) {
  int s = r & 511;
  int sg = ldi(seg, (size_t)r, fI), tp = ldi(typ, (size_t)r, fI);
  const f32x4* pr = (const f32x4*)((const float*)post + (size_t)s * 768);
  const f32x4* sr = (const f32x4*)((const float*)segt + (size_t)sg * 768);
  const f32x4* tr = (const f32x4*)((const float*)typt + (size_t)tp * 768);
  float sum = 0.f, sq = 0.f;
  f32x4 vv[3];
#pragma unroll
  for (int j = 0; j < 3; ++j) {
    int p = lane + 64 * j;
    f32x4 a = wsrc[j];
    a += pr[p]; a += sr[p]; a += tr[p];
    vv[j] = a;
#pragma unroll
    for (int c = 0; c < 4; ++c) { sum += a[c]; sq += a[c] * a[c]; }
  }
#pragma unroll
  for (int o = 32; o > 0; o >>= 1) { sum += __shfl_down(sum, o); sq += __shfl_down(sq, o); }
  sum = __shfl(sum, 0); sq = __shfl(sq, 0);
  float mu = sum * (1.f / 768.f);
  float var = fmaxf(sq * (1.f / 768.f) - mu * mu, 0.f);
  float rstd = rsqrtf(var + 1e-6f);
  const f32x4* gm = (const f32x4*)gamma;
  const f32x4* bt = (const f32x4*)beta;
  f32x4* orow = (f32x4*)(outp + (size_t)r * 768);
#pragma unroll
  for (int j = 0; j < 3; ++j) {
    int p = lane + 64 * j;
    f32x4 g4 = gm[p], b4 = bt[p], y;
#pragma unroll
    for (int c = 0; c < 4; ++c) y[c] = g4[c] * (vv[j][c] - mu) * rstd + b4[c];
    __builtin_nontemporal_store(y, &orow[p]);
  }
}

DEV void final_row_bf16(int r, int lane, const void* src, const void* seg,
                        const void* typ, const void* word, const void* post,
                        const void* segt, const void* typt, const void* gamma,
                        const void* beta, const float* xf, int fI,
                        unsigned short* __restrict__ outp) {
  int b = r >> 9, s = r & 511;
  int sg = ldi(seg, (size_t)r, fI), tp = ldi(typ, (size_t)r, fI);
  int wrow = ldi(src, (size_t)r, fI);
  bool cls = (s == 0);
  float sum = 0.f, sq = 0.f;
  float vs[12];
#pragma unroll
  for (int j = 0; j < 12; ++j) {
    int d = lane + 64 * j;
    float xv = cls ? xf[(size_t)b * 6912 + d] : ldf(word, (size_t)wrow * 768 + d, 0);
    xv += ldf(post, (size_t)s * 768 + d, 0);
    xv += ldf(segt, (size_t)sg * 768 + d, 0);
    xv += ldf(typt, (size_t)tp * 768 + d, 0);
    vs[j] = xv;
    sum += xv; sq += xv * xv;
  }
#pragma unroll
  for (int o = 32; o > 0; o >>= 1) { sum += __shfl_down(sum, o); sq += __shfl_down(sq, o); }
  sum = __shfl(sum, 0); sq = __shfl(sq, 0);
  float mu = sum * (1.f / 768.f);
  float var = fmaxf(sq * (1.f / 768.f) - mu * mu, 0.f);
  float rstd = rsqrtf(var + 1e-6f);
#pragma unroll
  for (int j = 0; j < 12; ++j) {
    int d = lane + 64 * j;
    float y = ldf(gamma, (size_t)d, 0) * (vs[j] - mu) * rstd + ldf(beta, (size_t)d, 0);
    outp[(size_t)r * 768 + d] = f2b(y);
  }
}

// ---------------------------------------------------------------------------
// k_gemm0f: layer-0 GEMM (blocks 0..467, 4 waves each) + ALL non-CLS final
// rows (blocks 468..2511: 4 waves x 4 rows = 16 rows/block, 32704 rows).
// Non-CLS rows depend only on input tables -> safe to run here. The 146 MB
// latency-bound stream hides under the GEMM dispatch's idle wave slots.
// ---------------------------------------------------------------------------
__global__ __launch_bounds__(256) void k_gemm0f(const unsigned short* __restrict__ xh,
                                                const unsigned short* __restrict__ xl,
                                                const unsigned short* __restrict__ Bh,
                                                const unsigned short* __restrict__ Bl,
                                                float* __restrict__ C,
                                                const void* __restrict__ src,
                                                const void* __restrict__ seg,
                                                const void* __restrict__ typ,
                                                const void* __restrict__ word,
                                                const void* __restrict__ post,
                                                const void* __restrict__ segt,
                                                const void* __restrict__ typt,
                                                const void* __restrict__ gamma,
                                                const void* __restrict__ beta,
                                                const int* __restrict__ flg,
                                                void* __restrict__ out) {
  int t = threadIdx.x, wave = t >> 6, lane = t & 63;
  if (blockIdx.x < 468) {
    gemm_wave(blockIdx.x * 4 + wave, lane, xh, xl, Bh, Bl, C);
    return;
  }
  int fF = flg[0], fI = flg[1];
  int wv = (blockIdx.x - 468) * 4 + wave;  // 0..8175
  // rows rid, rid+8176, rid+16352, rid+24528 ; rid -> r = b*512 + 1 + rid%511
  int rr[4];
#pragma unroll
  for (int k = 0; k < 4; ++k) {
    int rid = wv + 8176 * k;
    int b = rid / 511, s = 1 + (rid - b * 511);
    rr[k] = b * 512 + s;
  }
  if (fF) {
    // hoist all 4 scattered word-row gathers (never CLS here)
    const f32x4* wp[4];
#pragma unroll
    for (int k = 0; k < 4; ++k) {
      int w = ldi(src, (size_t)rr[k], fI);
      wp[k] = (const f32x4*)((const float*)word + (size_t)w * 768);
    }
    f32x4 wa[4][3];
#pragma unroll
    for (int k = 0; k < 4; ++k)
#pragma unroll
      for (int j = 0; j < 3; ++j) wa[k][j] = wp[k][lane + 64 * j];
#pragma unroll
    for (int k = 0; k < 4; ++k)
      final_row_f32(rr[k], lane, wa[k], seg, typ, post, segt, typt, gamma, beta, fI,
                    (float*)out);
  } else {
#pragma unroll
    for (int k = 0; k < 4; ++k)
      final_row_bf16(rr[k], lane, src, seg, typ, word, post, segt, typt, gamma, beta,
                     (const float*)nullptr, fI, (unsigned short*)out);
  }
}

// ---------------------------------------------------------------------------
// k_gat: identical to round 9.
// ---------------------------------------------------------------------------
__global__ __launch_bounds__(256) void k_gat(const float* __restrict__ C,
                                             const int* __restrict__ off,
                                             const int* __restrict__ srcs,
                                             const void* __restrict__ bG,
                                             const int* __restrict__ flg,
                                             int layer,
                                             float* __restrict__ xf,
                                             unsigned short* __restrict__ xh,
                                             unsigned short* __restrict__ xl) {
  int fF = flg[0];
  int idx = blockIdx.x * 256 + threadIdx.x;  // 576*768
  int n = idx / 768, d = idx - n * 768, h = d / 192;
  float aDv = C[(size_t)n * 832 + 772 + h];
  int e0 = off[n], e1 = off[n + 1];
  float num = 0.f, den = 0.f;
  for (int e = e0; e < e1; ++e) {
    int s = srcs[e];
    float lg = C[(size_t)s * 832 + 768 + h] + aDv;
    float lrel = lg < 0.f ? 0.2f * lg : lg;
    lrel = fminf(fmaxf(lrel, -60.f), 40.f);
    float w = __expf(lrel);
    num += w * C[(size_t)s * 832 + d];
    den += w;
  }
  float g = gelu_exact(num / den + ldf(bG, (size_t)layer * 768 + d, fF));
  xf[idx] = g;
  unsigned short hi = f2b(g);
  size_t o = frag_off(n, d);
  xh[o] = hi;
  xl[o] = f2b(g - b2f((unsigned int)hi));
}

// ---------------------------------------------------------------------------
// k_final_cls: the 64 CLS rows (need layer-4 xf). 16 blocks x 4 waves.
// ---------------------------------------------------------------------------
__global__ __launch_bounds__(256) void k_final_cls(const void* __restrict__ src,
                                                   const void* __restrict__ seg,
                                                   const void* __restrict__ typ,
                                                   const void* __restrict__ word,
                                                   const void* __restrict__ post,
                                                   const void* __restrict__ segt,
                                                   const void* __restrict__ typt,
                                                   const void* __restrict__ gamma,
                                                   const void* __restrict__ beta,
                                                   const float* __restrict__ xf,
                                                   const int* __restrict__ flg,
                                                   void* __restrict__ out) {
  int fF = flg[0], fI = flg[1];
  int wave = threadIdx.x >> 6, lane = threadIdx.x & 63;
  int b = blockIdx.x * 4 + wave;  // 0..63
  int r = b * 512;                // CLS row
  if (fF) {
    const f32x4* xr = (const f32x4*)(xf + (size_t)b * 6912);
    f32x4 wa[3];
#pragma unroll
    for (int j = 0; j < 3; ++j) wa[j] = xr[lane + 64 * j];
    final_row_f32(r, lane, wa, seg, typ, post, segt, typt, gamma, beta, fI, (float*)out);
  } else {
    final_row_bf16(r, lane, src, seg, typ, word, post, segt, typt, gamma, beta, xf, fI,
                   (unsigned short*)out);
  }
}

extern "C" void kernel_launch(void* const* d_in, const int* in_sizes, int n_in,
                              void* d_out, int out_size, void* d_ws, size_t ws_size,
                              hipStream_t stream) {
  const void* src  = d_in[0];
  const void* seg  = d_in[1];
  const void* typ  = d_in[2];
  const void* pos  = d_in[3];
  const void* sst  = d_in[4];
  const void* sen  = d_in[5];
  const void* edge = d_in[6];
  const void* word = d_in[7];
  const void* post = d_in[8];
  const void* segt = d_in[9];
  const void* typt = d_in[10];
  const void* gamma = d_in[11];
  const void* beta  = d_in[12];
  const void* Wg    = d_in[13];
  const void* aS    = d_in[14];
  const void* aD    = d_in[15];
  const void* bG    = d_in[16];

  char* ws = (char*)d_ws;
  float* xf = (float*)(ws);                               //  1,769,472
  float* C  = (float*)(ws + 1769472);                     //  1,916,928
  unsigned short* xh = (unsigned short*)(ws + 3686400);   //    884,736 (frag-linear)
  unsigned short* xl = (unsigned short*)(ws + 4571136);   //    884,736
  unsigned short* Bh = (unsigned short*)(ws + 5455872);   //  6,389,760 (5 layers, frag-linear)
  unsigned short* Bl = (unsigned short*)(ws + 11845632);  //  6,389,760
  int* csr_off = (int*)(ws + 18358272);                   //      2,320 (pad)
  int* csr_src = (int*)(ws + 18360592);                   //     35,072
  int* flags   = (int*)(ws + 18395664);                   //          8

  k_front<<<dim3(1357), dim3(256), 0, stream>>>(src, sst, sen, edge, word, pos, aS, aD, Wg,
                                                xh, xl, Bh, Bl, csr_off, csr_src, flags);
  // layer 0 GEMM + all non-CLS final rows in one dispatch
  k_gemm0f<<<dim3(2512), dim3(256), 0, stream>>>(xh, xl, Bh, Bl, C,
                                                 src, seg, typ, word, post, segt, typt,
                                                 gamma, beta, flags, d_out);
  k_gat<<<dim3(1728), dim3(256), 0, stream>>>(C, csr_off, csr_src, bG, flags, 0, xf, xh, xl);
  for (int l = 1; l < 5; ++l) {
    k_gemm<<<dim3(1872), dim3(64), 0, stream>>>(xh, xl,
                                                Bh + (size_t)l * 832 * 768,
                                                Bl + (size_t)l * 832 * 768, C);
    k_gat<<<dim3(1728), dim3(256), 0, stream>>>(C, csr_off, csr_src, bG, flags, l, xf, xh, xl);
  }
  k_final_cls<<<dim3(16), dim3(256), 0, stream>>>(src, seg, typ, word, post, segt, typt,
                                                  gamma, beta, xf, flags, d_out);
}

// Round 6
// 395.887 us; speedup vs baseline: 1.0099x; 1.0099x over previous
//
#include <hip/hip_runtime.h>

// BertEmbedding + 5-layer GAT on MI355X (gfx950). Round 12 (resubmit —
// round-13 bench hit GPUAcquisitionTimeout, kernel never ran):
//  - Round-10 post-mortem: fusing final rows into the layer-0 GEMM dispatch
//    was neutral-to-negative (69us fused vs 59.5+10us separate; BW pinned at
//    ~2.5 TB/s in BOTH configs, across occupancy 62%->26% and 1/2/4 rows per
//    wave). Not latency-bound -> path/instruction cap. Reverted to round-9
//    structure (measured best: 389us).
//  - A/B this round: k_final uses PLAIN stores (nontemporal dropped). nt was
//    added in round 7 with no isolated win (485.6->487.0); fillBuffer hits
//    6.7 TB/s with plain stores while our nt-store stream caps at 2.5.
//  - k_gemm: 1872 x 64-thread one-wave blocks for all 5 layers (validated
//    for layers 1-4 in the passing round-10 run; even 7.3 waves/CU fill).
//  - Everything else byte-identical to the passing round-9 kernel.

#define DEV __device__ __forceinline__

typedef short s16x8 __attribute__((ext_vector_type(8)));
typedef float f32x4 __attribute__((ext_vector_type(4)));
typedef unsigned short u16x8 __attribute__((ext_vector_type(8)));

DEV float b2f(unsigned int u) { union { unsigned int i; float f; } v; v.i = u << 16; return v.f; }
DEV unsigned short f2b(float f) {
  union { float f; unsigned int i; } v; v.f = f;
  return (unsigned short)((v.i + 0x7fffu + ((v.i >> 16) & 1u)) >> 16);
}
DEV float gelu_exact(float x) { return 0.5f * x * (1.f + erff(x * 0.70710678118654752f)); }

// dual-dtype loads. fF: floats are f32 (else bf16). fI: ints are int64.
DEV float ldf(const void* p, size_t i, int fF) {
  return fF ? ((const float*)p)[i] : b2f(((const unsigned short*)p)[i]);
}
DEV int ldi(const void* p, size_t i, int fI) {
  return fI ? ((const int*)p)[2 * i] : ((const int*)p)[i];
}

// Fragment-linear offset for element [n][d] of a [rows][768] matrix.
DEV size_t frag_off(int n, int d) {
  return ((((size_t)(n >> 4) * 24 + (size_t)(d >> 5)) * 64 +
           (((d >> 3) & 3) << 4) + (n & 15)) << 3) + (d & 7);
}

// ---------------------------------------------------------------------------
// k_front: fused front-end, 1357 blocks (identical to round 9).
// ---------------------------------------------------------------------------
__global__ __launch_bounds__(256) void k_front(const void* __restrict__ src,
                                               const void* __restrict__ sst,
                                               const void* __restrict__ sen,
                                               const void* __restrict__ edge,
                                               const void* __restrict__ word,
                                               const void* __restrict__ pos,
                                               const void* __restrict__ aS,
                                               const void* __restrict__ aD,
                                               const void* __restrict__ Wg,
                                               unsigned short* __restrict__ xh,
                                               unsigned short* __restrict__ xl,
                                               unsigned short* __restrict__ Bh,
                                               unsigned short* __restrict__ Bl,
                                               int* __restrict__ csr_off,
                                               int* __restrict__ csr_src,
                                               int* __restrict__ flags) {
  __shared__ int sflags[2];
  __shared__ float tile[64][65];
  __shared__ float sA[768], sD[768];
  __shared__ int cnt[576], off[577], fill[576];
  int t = threadIdx.x, bid = blockIdx.x;
  if (t < 64) {
    const unsigned short* w16 = (const unsigned short*)word;
    int crazy = 0;
    for (int i = t; i < 512; i += 64) {
      unsigned int e = (w16[i] >> 7) & 0xffu;
      if (e >= 135u || (e >= 1u && e <= 100u)) crazy++;
    }
#pragma unroll
    for (int o = 32; o > 0; o >>= 1) crazy += __shfl_down(crazy, o);
    if (t == 0) {
      sflags[0] = (crazy >= 8) ? 1 : 0;
      sflags[1] = (((const int*)pos)[1] == 0) ? 1 : 0;
    }
  }
  __syncthreads();
  int fF = sflags[0], fI = sflags[1];
  if (bid == 0 && t == 0) { flags[0] = fF; flags[1] = fI; }

  if (bid < 780) {
    int layer = bid / 156, r = bid % 156, kt = r / 13, nt = r % 13;
    int k0 = kt * 64, n0 = nt * 64;
    if (nt < 12) {
#pragma unroll
      for (int i = 0; i < 16; ++i) {
        int e = t + 256 * i, rk = e >> 6, cn = e & 63;
        tile[rk][cn] = ldf(Wg, ((size_t)layer * 768 + k0 + rk) * 768 + n0 + cn, fF);
      }
    } else {
      for (int i = t; i < 768; i += 256) {
        sA[i] = ldf(aS, (size_t)layer * 768 + i, fF);
        sD[i] = ldf(aD, (size_t)layer * 768 + i, fF);
      }
#pragma unroll
      for (int i = 0; i < 16; ++i) {
        int e = t + 256 * i, rk = e >> 6, cn = e & 63;
        if (cn >= 8) tile[rk][cn] = 0.f;
      }
      __syncthreads();
      int wave = t >> 6, lane = t & 63;
      for (int rr = 0; rr < 16; ++rr) {
        int rk = wave * 16 + rr;
        size_t wbase = ((size_t)layer * 768 + k0 + rk) * 768;
        float accS[4] = {0.f, 0.f, 0.f, 0.f}, accD[4] = {0.f, 0.f, 0.f, 0.f};
#pragma unroll
        for (int i = 0; i < 12; ++i) {
          int d = lane + 64 * i;
          float w = ldf(Wg, wbase + d, fF);
          accS[i / 3] += w * sA[d];
          accD[i / 3] += w * sD[d];
        }
#pragma unroll
        for (int h = 0; h < 4; ++h) {
          float sS = accS[h], sDv = accD[h];
#pragma unroll
          for (int o = 32; o > 0; o >>= 1) {
            sS += __shfl_down(sS, o);
            sDv += __shfl_down(sDv, o);
          }
          if (lane == 0) { tile[rk][h] = sS; tile[rk][4 + h] = sDv; }
        }
      }
    }
    __syncthreads();
    size_t lb = (size_t)layer * 79872;
#pragma unroll
    for (int g = 0; g < 2; ++g) {
      int G = t * 2 + g, rn = G & 63, c8 = G >> 6;
      int n = n0 + rn, kb = k0 + c8 * 8;
      u16x8 hv, lv;
#pragma unroll
      for (int j = 0; j < 8; ++j) {
        float v = tile[c8 * 8 + j][rn];
        unsigned short hi = f2b(v);
        hv[j] = hi;
        lv[j] = f2b(v - b2f((unsigned int)hi));
      }
      size_t go = lb + ((size_t)(n >> 4) * 24 + (size_t)(kb >> 5)) * 64 +
                  (((kb >> 3) & 3) << 4) + (n & 15);
      *(u16x8*)(Bh + go * 8) = hv;
      *(u16x8*)(Bl + go * 8) = lv;
    }
  } else if (bid < 1356) {
    int g = bid - 780;
    int b = g / 9, j = g % 9;
    float v[3] = {0.f, 0.f, 0.f};
    if (j == 0) {
      int rr = ldi(src, (size_t)b * 512, fI);
#pragma unroll
      for (int ii = 0; ii < 3; ++ii) v[ii] = ldf(word, (size_t)rr * 768 + t + 256 * ii, fF);
    } else {
      int st = ldi(sst, (size_t)b * 8 + j - 1, fI);
      int en = ldi(sen, (size_t)b * 8 + j - 1, fI);
      for (int s = st; s <= en; ++s) {
        int rr = ldi(src, (size_t)b * 512 + s, fI);
#pragma unroll
        for (int ii = 0; ii < 3; ++ii) v[ii] += ldf(word, (size_t)rr * 768 + t + 256 * ii, fF);
      }
    }
#pragma unroll
    for (int ii = 0; ii < 3; ++ii) {
      int d = t + 256 * ii;
      unsigned short hi = f2b(v[ii]);
      size_t o = frag_off(g, d);
      xh[o] = hi;
      xl[o] = f2b(v[ii] - b2f((unsigned int)hi));
    }
  } else {
    for (int i = t; i < 576; i += 256) cnt[i] = 0;
    __syncthreads();
    for (int e = t; e < 8768; e += 256) {
      int di;
      if (e < 4096) di = ldi(edge, (size_t)4096 + e, fI);
      else if (e < 8192) di = ldi(edge, (size_t)e - 4096, fI);
      else di = e - 8192;
      atomicAdd(&cnt[di], 1);
    }
    __syncthreads();
    if (t == 0) {
      int a = 0;
      for (int i = 0; i < 576; ++i) { off[i] = a; a += cnt[i]; }
      off[576] = a;
    }
    __syncthreads();
    for (int i = t; i < 577; i += 256) csr_off[i] = off[i];
    for (int i = t; i < 576; i += 256) fill[i] = off[i];
    __syncthreads();
    for (int e = t; e < 8768; e += 256) {
      int si, di;
      if (e < 4096)      { si = ldi(edge, (size_t)e, fI); di = ldi(edge, (size_t)4096 + e, fI); }
      else if (e < 8192) { si = ldi(edge, (size_t)e, fI); di = ldi(edge, (size_t)e - 4096, fI); }
      else               { si = e - 8192;                 di = si; }
      int p = atomicAdd(&fill[di], 1);
      csr_src[p] = si;
    }
  }
}

// ---------------------------------------------------------------------------
// k_gemm: one wave per 16x16 C-tile, LDS-free, barrier-free, 3 MFMA chains.
// 1872 one-wave blocks -> even ~7.3 waves/CU (all 5 layers).
// ---------------------------------------------------------------------------
__global__ __launch_bounds__(64) void k_gemm(const unsigned short* __restrict__ xh,
                                             const unsigned short* __restrict__ xl,
                                             const unsigned short* __restrict__ Bh,
                                             const unsigned short* __restrict__ Bl,
                                             float* __restrict__ C) {
  int lane = threadIdx.x & 63;
  int wid = blockIdx.x;
  int rt = wid / 52, ct = wid % 52;
  const s16x8* Ah = (const s16x8*)xh + (size_t)rt * 1536 + lane;
  const s16x8* Al = (const s16x8*)xl + (size_t)rt * 1536 + lane;
  const s16x8* Bhp = (const s16x8*)Bh + (size_t)ct * 1536 + lane;
  const s16x8* Blp = (const s16x8*)Bl + (size_t)ct * 1536 + lane;
  f32x4 a0 = {0.f, 0.f, 0.f, 0.f}, a1 = a0, a2 = a0;
#pragma unroll 6
  for (int kk = 0; kk < 24; ++kk) {
    s16x8 ah = Ah[kk * 64];
    s16x8 al = Al[kk * 64];
    s16x8 bh = Bhp[kk * 64];
    s16x8 bl = Blp[kk * 64];
    a0 = __builtin_amdgcn_mfma_f32_16x16x32_bf16(ah, bh, a0, 0, 0, 0);
    a1 = __builtin_amdgcn_mfma_f32_16x16x32_bf16(ah, bl, a1, 0, 0, 0);
    a2 = __builtin_amdgcn_mfma_f32_16x16x32_bf16(al, bh, a2, 0, 0, 0);
  }
  int row0 = rt * 16 + (lane >> 4) * 4, col = ct * 16 + (lane & 15);
#pragma unroll
  for (int r = 0; r < 4; ++r)
    C[(size_t)(row0 + r) * 832 + col] = a0[r] + a1[r] + a2[r];
}

// ---------------------------------------------------------------------------
// k_gat: one thread per (node, feature). Identical to round 9.
// ---------------------------------------------------------------------------
__global__ __launch_bounds__(256) void k_gat(const float* __restrict__ C,
                                             const int* __restrict__ off,
                                             const int* __restrict__ srcs,
                                             const void* __restrict__ bG,
                                             const int* __restrict__ flg,
                                             int layer,
                                             float* __restrict__ xf,
                                             unsigned short* __restrict__ xh,
                                             unsigned short* __restrict__ xl) {
  int fF = flg[0];
  int idx = blockIdx.x * 256 + threadIdx.x;  // 576*768
  int n = idx / 768, d = idx - n * 768, h = d / 192;
  float aDv = C[(size_t)n * 832 + 772 + h];
  int e0 = off[n], e1 = off[n + 1];
  float num = 0.f, den = 0.f;
  for (int e = e0; e < e1; ++e) {
    int s = srcs[e];
    float lg = C[(size_t)s * 832 + 768 + h] + aDv;
    float lrel = lg < 0.f ? 0.2f * lg : lg;
    lrel = fminf(fmaxf(lrel, -60.f), 40.f);
    float w = __expf(lrel);
    num += w * C[(size_t)s * 832 + d];
    den += w;
  }
  float g = gelu_exact(num / den + ldf(bG, (size_t)layer * 768 + d, fF));
  xf[idx] = g;
  unsigned short hi = f2b(g);
  size_t o = frag_off(n, d);
  xh[o] = hi;
  xl[o] = f2b(g - b2f((unsigned int)hi));
}

// ---------------------------------------------------------------------------
// k_final: emb = (CLS? gnn_x : word[src]) + pos + seg + type; LayerNorm.
// Wave handles TWO rows (r, r+16384), both rows' gathers hoisted.
// A/B this round: PLAIN stores (nontemporal dropped — testing the 2.5 TB/s
// cap theory; nt was never an isolated win).
// ---------------------------------------------------------------------------
DEV void final_row_f32(int r, int lane, const f32x4* wsrc,
                       const void* seg, const void* typ, const void* post,
                       const void* segt, const void* typt,
                       const void* gamma, const void* beta, int fI,
                       float* __restrict__ outp) {
  int s = r & 511;
  int sg = ldi(seg, (size_t)r, fI), tp = ldi(typ, (size_t)r, fI);
  const f32x4* pr = (const f32x4*)((const float*)post + (size_t)s * 768);
  const f32x4* sr = (const f32x4*)((const float*)segt + (size_t)sg * 768);
  const f32x4* tr = (const f32x4*)((const float*)typt + (size_t)tp * 768);
  float sum = 0.f, sq = 0.f;
  f32x4 vv[3];
#pragma unroll
  for (int j = 0; j < 3; ++j) {
    int p = lane + 64 * j;
    f32x4 a = wsrc[j];
    a += pr[p]; a += sr[p]; a += tr[p];
    vv[j] = a;
#pragma unroll
    for (int c = 0; c < 4; ++c) { sum += a[c]; sq += a[c] * a[c]; }
  }
#pragma unroll
  for (int o = 32; o > 0; o >>= 1) { sum += __shfl_down(sum, o); sq += __shfl_down(sq, o); }
  sum = __shfl(sum, 0); sq = __shfl(sq, 0);
  float mu = sum * (1.f / 768.f);
  float var = fmaxf(sq * (1.f / 768.f) - mu * mu, 0.f);
  float rstd = rsqrtf(var + 1e-6f);
  const f32x4* gm = (const f32x4*)gamma;
  const f32x4* bt = (const f32x4*)beta;
  f32x4* orow = (f32x4*)(outp + (size_t)r * 768);
#pragma unroll
  for (int j = 0; j < 3; ++j) {
    int p = lane + 64 * j;
    f32x4 g4 = gm[p], b4 = bt[p], y;
#pragma unroll
    for (int c = 0; c < 4; ++c) y[c] = g4[c] * (vv[j][c] - mu) * rstd + b4[c];
    orow[p] = y;  // plain store (nt dropped for A/B)
  }
}

DEV void final_row_bf16(int r, int lane, const void* src, const void* seg,
                        const void* typ, const void* word, const void* post,
                        const void* segt, const void* typt, const void* gamma,
                        const void* beta, const float* xf, int fI,
                        unsigned short* __restrict__ outp) {
  int b = r >> 9, s = r & 511;
  int sg = ldi(seg, (size_t)r, fI), tp = ldi(typ, (size_t)r, fI);
  int wrow = ldi(src, (size_t)r, fI);
  bool cls = (s == 0);
  float sum = 0.f, sq = 0.f;
  float vs[12];
#pragma unroll
  for (int j = 0; j < 12; ++j) {
    int d = lane + 64 * j;
    float xv = cls ? xf[(size_t)b * 6912 + d] : ldf(word, (size_t)wrow * 768 + d, 0);
    xv += ldf(post, (size_t)s * 768 + d, 0);
    xv += ldf(segt, (size_t)sg * 768 + d, 0);
    xv += ldf(typt, (size_t)tp * 768 + d, 0);
    vs[j] = xv;
    sum += xv; sq += xv * xv;
  }
#pragma unroll
  for (int o = 32; o > 0; o >>= 1) { sum += __shfl_down(sum, o); sq += __shfl_down(sq, o); }
  sum = __shfl(sum, 0); sq = __shfl(sq, 0);
  float mu = sum * (1.f / 768.f);
  float var = fmaxf(sq * (1.f / 768.f) - mu * mu, 0.f);
  float rstd = rsqrtf(var + 1e-6f);
#pragma unroll
  for (int j = 0; j < 12; ++j) {
    int d = lane + 64 * j;
    float y = ldf(gamma, (size_t)d, 0) * (vs[j] - mu) * rstd + ldf(beta, (size_t)d, 0);
    outp[(size_t)r * 768 + d] = f2b(y);
  }
}

__global__ __launch_bounds__(256) void k_final(const void* __restrict__ src,
                                               const void* __restrict__ seg,
                                               const void* __restrict__ typ,
                                               const void* __restrict__ word,
                                               const void* __restrict__ post,
                                               const void* __restrict__ segt,
                                               const void* __restrict__ typt,
                                               const void* __restrict__ gamma,
                                               const void* __restrict__ beta,
                                               const float* __restrict__ xf,
                                               const int* __restrict__ flg,
                                               void* __restrict__ out) {
  int fF = flg[0], fI = flg[1];
  int wave = threadIdx.x >> 6, lane = threadIdx.x & 63;
  int r0 = blockIdx.x * 4 + wave, r1 = r0 + 16384;
  if (fF) {
    int s0 = r0 & 511, s1 = r1 & 511;
    int b0 = r0 >> 9, b1 = r1 >> 9;
    int w0r = ldi(src, (size_t)r0, fI), w1r = ldi(src, (size_t)r1, fI);
    const f32x4* p0 = (s0 == 0) ? (const f32x4*)(xf + (size_t)b0 * 6912)
                                : (const f32x4*)((const float*)word + (size_t)w0r * 768);
    const f32x4* p1 = (s1 == 0) ? (const f32x4*)(xf + (size_t)b1 * 6912)
                                : (const f32x4*)((const float*)word + (size_t)w1r * 768);
    f32x4 wa[3], wb[3];
#pragma unroll
    for (int j = 0; j < 3; ++j) { wa[j] = p0[lane + 64 * j]; wb[j] = p1[lane + 64 * j]; }
    final_row_f32(r0, lane, wa, seg, typ, post, segt, typt, gamma, beta, fI, (float*)out);
    final_row_f32(r1, lane, wb, seg, typ, post, segt, typt, gamma, beta, fI, (float*)out);
  } else {
    final_row_bf16(r0, lane, src, seg, typ, word, post, segt, typt, gamma, beta, xf, fI,
                   (unsigned short*)out);
    final_row_bf16(r1, lane, src, seg, typ, word, post, segt, typt, gamma, beta, xf, fI,
                   (unsigned short*)out);
  }
}

extern "C" void kernel_launch(void* const* d_in, const int* in_sizes, int n_in,
                              void* d_out, int out_size, void* d_ws, size_t ws_size,
                              hipStream_t stream) {
  const void* src  = d_in[0];
  const void* seg  = d_in[1];
  const void* typ  = d_in[2];
  const void* pos  = d_in[3];
  const void* sst  = d_in[4];
  const void* sen  = d_in[5];
  const void* edge = d_in[6];
  const void* word = d_in[7];
  const void* post = d_in[8];
  const void* segt = d_in[9];
  const void* typt = d_in[10];
  const void* gamma = d_in[11];
  const void* beta  = d_in[12];
  const void* Wg    = d_in[13];
  const void* aS    = d_in[14];
  const void* aD    = d_in[15];
  const void* bG    = d_in[16];

  char* ws = (char*)d_ws;
  float* xf = (float*)(ws);                               //  1,769,472
  float* C  = (float*)(ws + 1769472);                     //  1,916,928
  unsigned short* xh = (unsigned short*)(ws + 3686400);   //    884,736 (frag-linear)
  unsigned short* xl = (unsigned short*)(ws + 4571136);   //    884,736
  unsigned short* Bh = (unsigned short*)(ws + 5455872);   //  6,389,760 (5 layers, frag-linear)
  unsigned short* Bl = (unsigned short*)(ws + 11845632);  //  6,389,760
  int* csr_off = (int*)(ws + 18358272);                   //      2,320 (pad)
  int* csr_src = (int*)(ws + 18360592);                   //     35,072
  int* flags   = (int*)(ws + 18395664);                   //          8

  k_front<<<dim3(1357), dim3(256), 0, stream>>>(src, sst, sen, edge, word, pos, aS, aD, Wg,
                                                xh, xl, Bh, Bl, csr_off, csr_src, flags);
  for (int l = 0; l < 5; ++l) {
    k_gemm<<<dim3(1872), dim3(64), 0, stream>>>(xh, xl,
                                                Bh + (size_t)l * 832 * 768,
                                                Bl + (size_t)l * 832 * 768, C);
    k_gat<<<dim3(1728), dim3(256), 0, stream>>>(C, csr_off, csr_src, bG, flags, l, xf, xh, xl);
  }
  k_final<<<dim3(4096), dim3(256), 0, stream>>>(src, seg, typ, word, post, segt, typt,
                                                gamma, beta, xf, flags, d_out);
}

// Round 7
// 364.161 us; speedup vs baseline: 1.0978x; 1.0871x over previous
//
#include <hip/hip_runtime.h>

// BertEmbedding + 5-layer GAT on MI355X (gfx950). Round 14:
//  - Budget (validated across rounds 7-12): ~180us harness poison-fills are
//    INSIDE the timed region (fixed floor); dispatch gaps ~0; addressable
//    kernel time ~209us: front ~45, 5xgemm ~50, 5xgat ~55, final 59.
//  - Round-12 A/B: plain vs nt stores = +7us (nt better / noise). k_final's
//    2.5 TB/s survives occupancy/rows-per-wave/fusion/store-type -> treat as
//    pattern ceiling. Reverted to the measured-best round-9 config for
//    front/gemm/final (nt stores, 468x4-wave gemm).
//  - This round changes ONLY the GAT family (clean attribution):
//    * layers 0-3: drop dead xf write (only layer-4 xf is ever read).
//    * layer 4: only the 64 text-node rows are consumed -> 192-block slim
//      kernel, xf-only output (xh/xl dead after layer 4).
//    * edge loop: 4-deep load batching (all 8 gathers of a 4-edge chunk
//      issued before the exp chain); accumulation order unchanged ->
//      bit-identical results.

#define DEV __device__ __forceinline__

typedef short s16x8 __attribute__((ext_vector_type(8)));
typedef float f32x4 __attribute__((ext_vector_type(4)));
typedef unsigned short u16x8 __attribute__((ext_vector_type(8)));

DEV float b2f(unsigned int u) { union { unsigned int i; float f; } v; v.i = u << 16; return v.f; }
DEV unsigned short f2b(float f) {
  union { float f; unsigned int i; } v; v.f = f;
  return (unsigned short)((v.i + 0x7fffu + ((v.i >> 16) & 1u)) >> 16);
}
DEV float gelu_exact(float x) { return 0.5f * x * (1.f + erff(x * 0.70710678118654752f)); }

// dual-dtype loads. fF: floats are f32 (else bf16). fI: ints are int64.
DEV float ldf(const void* p, size_t i, int fF) {
  return fF ? ((const float*)p)[i] : b2f(((const unsigned short*)p)[i]);
}
DEV int ldi(const void* p, size_t i, int fI) {
  return fI ? ((const int*)p)[2 * i] : ((const int*)p)[i];
}

// Fragment-linear offset for element [n][d] of a [rows][768] matrix.
DEV size_t frag_off(int n, int d) {
  return ((((size_t)(n >> 4) * 24 + (size_t)(d >> 5)) * 64 +
           (((d >> 3) & 3) << 4) + (n & 15)) << 3) + (d & 7);
}

// ---------------------------------------------------------------------------
// k_front: fused front-end, 1357 blocks (identical to round 9).
// ---------------------------------------------------------------------------
__global__ __launch_bounds__(256) void k_front(const void* __restrict__ src,
                                               const void* __restrict__ sst,
                                               const void* __restrict__ sen,
                                               const void* __restrict__ edge,
                                               const void* __restrict__ word,
                                               const void* __restrict__ pos,
                                               const void* __restrict__ aS,
                                               const void* __restrict__ aD,
                                               const void* __restrict__ Wg,
                                               unsigned short* __restrict__ xh,
                                               unsigned short* __restrict__ xl,
                                               unsigned short* __restrict__ Bh,
                                               unsigned short* __restrict__ Bl,
                                               int* __restrict__ csr_off,
                                               int* __restrict__ csr_src,
                                               int* __restrict__ flags) {
  __shared__ int sflags[2];
  __shared__ float tile[64][65];
  __shared__ float sA[768], sD[768];
  __shared__ int cnt[576], off[577], fill[576];
  int t = threadIdx.x, bid = blockIdx.x;
  if (t < 64) {
    const unsigned short* w16 = (const unsigned short*)word;
    int crazy = 0;
    for (int i = t; i < 512; i += 64) {
      unsigned int e = (w16[i] >> 7) & 0xffu;
      if (e >= 135u || (e >= 1u && e <= 100u)) crazy++;
    }
#pragma unroll
    for (int o = 32; o > 0; o >>= 1) crazy += __shfl_down(crazy, o);
    if (t == 0) {
      sflags[0] = (crazy >= 8) ? 1 : 0;
      sflags[1] = (((const int*)pos)[1] == 0) ? 1 : 0;
    }
  }
  __syncthreads();
  int fF = sflags[0], fI = sflags[1];
  if (bid == 0 && t == 0) { flags[0] = fF; flags[1] = fI; }

  if (bid < 780) {
    int layer = bid / 156, r = bid % 156, kt = r / 13, nt = r % 13;
    int k0 = kt * 64, n0 = nt * 64;
    if (nt < 12) {
#pragma unroll
      for (int i = 0; i < 16; ++i) {
        int e = t + 256 * i, rk = e >> 6, cn = e & 63;
        tile[rk][cn] = ldf(Wg, ((size_t)layer * 768 + k0 + rk) * 768 + n0 + cn, fF);
      }
    } else {
      for (int i = t; i < 768; i += 256) {
        sA[i] = ldf(aS, (size_t)layer * 768 + i, fF);
        sD[i] = ldf(aD, (size_t)layer * 768 + i, fF);
      }
#pragma unroll
      for (int i = 0; i < 16; ++i) {
        int e = t + 256 * i, rk = e >> 6, cn = e & 63;
        if (cn >= 8) tile[rk][cn] = 0.f;
      }
      __syncthreads();
      int wave = t >> 6, lane = t & 63;
      for (int rr = 0; rr < 16; ++rr) {
        int rk = wave * 16 + rr;
        size_t wbase = ((size_t)layer * 768 + k0 + rk) * 768;
        float accS[4] = {0.f, 0.f, 0.f, 0.f}, accD[4] = {0.f, 0.f, 0.f, 0.f};
#pragma unroll
        for (int i = 0; i < 12; ++i) {
          int d = lane + 64 * i;
          float w = ldf(Wg, wbase + d, fF);
          accS[i / 3] += w * sA[d];
          accD[i / 3] += w * sD[d];
        }
#pragma unroll
        for (int h = 0; h < 4; ++h) {
          float sS = accS[h], sDv = accD[h];
#pragma unroll
          for (int o = 32; o > 0; o >>= 1) {
            sS += __shfl_down(sS, o);
            sDv += __shfl_down(sDv, o);
          }
          if (lane == 0) { tile[rk][h] = sS; tile[rk][4 + h] = sDv; }
        }
      }
    }
    __syncthreads();
    size_t lb = (size_t)layer * 79872;
#pragma unroll
    for (int g = 0; g < 2; ++g) {
      int G = t * 2 + g, rn = G & 63, c8 = G >> 6;
      int n = n0 + rn, kb = k0 + c8 * 8;
      u16x8 hv, lv;
#pragma unroll
      for (int j = 0; j < 8; ++j) {
        float v = tile[c8 * 8 + j][rn];
        unsigned short hi = f2b(v);
        hv[j] = hi;
        lv[j] = f2b(v - b2f((unsigned int)hi));
      }
      size_t go = lb + ((size_t)(n >> 4) * 24 + (size_t)(kb >> 5)) * 64 +
                  (((kb >> 3) & 3) << 4) + (n & 15);
      *(u16x8*)(Bh + go * 8) = hv;
      *(u16x8*)(Bl + go * 8) = lv;
    }
  } else if (bid < 1356) {
    int g = bid - 780;
    int b = g / 9, j = g % 9;
    float v[3] = {0.f, 0.f, 0.f};
    if (j == 0) {
      int rr = ldi(src, (size_t)b * 512, fI);
#pragma unroll
      for (int ii = 0; ii < 3; ++ii) v[ii] = ldf(word, (size_t)rr * 768 + t + 256 * ii, fF);
    } else {
      int st = ldi(sst, (size_t)b * 8 + j - 1, fI);
      int en = ldi(sen, (size_t)b * 8 + j - 1, fI);
      for (int s = st; s <= en; ++s) {
        int rr = ldi(src, (size_t)b * 512 + s, fI);
#pragma unroll
        for (int ii = 0; ii < 3; ++ii) v[ii] += ldf(word, (size_t)rr * 768 + t + 256 * ii, fF);
      }
    }
#pragma unroll
    for (int ii = 0; ii < 3; ++ii) {
      int d = t + 256 * ii;
      unsigned short hi = f2b(v[ii]);
      size_t o = frag_off(g, d);
      xh[o] = hi;
      xl[o] = f2b(v[ii] - b2f((unsigned int)hi));
    }
  } else {
    for (int i = t; i < 576; i += 256) cnt[i] = 0;
    __syncthreads();
    for (int e = t; e < 8768; e += 256) {
      int di;
      if (e < 4096) di = ldi(edge, (size_t)4096 + e, fI);
      else if (e < 8192) di = ldi(edge, (size_t)e - 4096, fI);
      else di = e - 8192;
      atomicAdd(&cnt[di], 1);
    }
    __syncthreads();
    if (t == 0) {
      int a = 0;
      for (int i = 0; i < 576; ++i) { off[i] = a; a += cnt[i]; }
      off[576] = a;
    }
    __syncthreads();
    for (int i = t; i < 577; i += 256) csr_off[i] = off[i];
    for (int i = t; i < 576; i += 256) fill[i] = off[i];
    __syncthreads();
    for (int e = t; e < 8768; e += 256) {
      int si, di;
      if (e < 4096)      { si = ldi(edge, (size_t)e, fI); di = ldi(edge, (size_t)4096 + e, fI); }
      else if (e < 8192) { si = ldi(edge, (size_t)e, fI); di = ldi(edge, (size_t)e - 4096, fI); }
      else               { si = e - 8192;                 di = si; }
      int p = atomicAdd(&fill[di], 1);
      csr_src[p] = si;
    }
  }
}

// ---------------------------------------------------------------------------
// k_gemm: round-9 exact. 468 blocks x 4 waves, one 16x16 C-tile per wave,
// LDS-free, barrier-free, 3 MFMA chains.
// ---------------------------------------------------------------------------
__global__ __launch_bounds__(256) void k_gemm(const unsigned short* __restrict__ xh,
                                              const unsigned short* __restrict__ xl,
                                              const unsigned short* __restrict__ Bh,
                                              const unsigned short* __restrict__ Bl,
                                              float* __restrict__ C) {
  int t = threadIdx.x;
  int wid = blockIdx.x * 4 + (t >> 6), lane = t & 63;
  int rt = wid / 52, ct = wid % 52;
  const s16x8* Ah = (const s16x8*)xh + (size_t)rt * 1536 + lane;
  const s16x8* Al = (const s16x8*)xl + (size_t)rt * 1536 + lane;
  const s16x8* Bhp = (const s16x8*)Bh + (size_t)ct * 1536 + lane;
  const s16x8* Blp = (const s16x8*)Bl + (size_t)ct * 1536 + lane;
  f32x4 a0 = {0.f, 0.f, 0.f, 0.f}, a1 = a0, a2 = a0;
#pragma unroll 6
  for (int kk = 0; kk < 24; ++kk) {
    s16x8 ah = Ah[kk * 64];
    s16x8 al = Al[kk * 64];
    s16x8 bh = Bhp[kk * 64];
    s16x8 bl = Blp[kk * 64];
    a0 = __builtin_amdgcn_mfma_f32_16x16x32_bf16(ah, bh, a0, 0, 0, 0);
    a1 = __builtin_amdgcn_mfma_f32_16x16x32_bf16(ah, bl, a1, 0, 0, 0);
    a2 = __builtin_amdgcn_mfma_f32_16x16x32_bf16(al, bh, a2, 0, 0, 0);
  }
  int row0 = rt * 16 + (lane >> 4) * 4, col = ct * 16 + (lane & 15);
#pragma unroll
  for (int r = 0; r < 4; ++r)
    C[(size_t)(row0 + r) * 832 + col] = a0[r] + a1[r] + a2[r];
}

// ---------------------------------------------------------------------------
// GAT aggregate: softmax-weighted sum over CSR neighbors. 4-deep load
// batching: all 8 gathers of a chunk issue before the exp chain. Accumulation
// order identical to the scalar loop -> bit-identical results. The e1 bound
// is wave-uniform (each wave lies inside one n: 768 = 12 waves).
// ---------------------------------------------------------------------------
DEV float gat_aggregate(const float* __restrict__ C, const int* __restrict__ off,
                        const int* __restrict__ srcs, int n, int d, int h) {
  float aDv = C[(size_t)n * 832 + 772 + h];
  int e0 = off[n], e1 = off[n + 1];
  float num = 0.f, den = 0.f;
  for (int e = e0; e < e1; e += 4) {
    float lg[4], ms[4];
#pragma unroll
    for (int j = 0; j < 4; ++j) {
      int ee = (e + j < e1) ? (e + j) : e0;  // clamp; tail lanes skip compute
      int s = srcs[ee];
      lg[j] = C[(size_t)s * 832 + 768 + h];
      ms[j] = C[(size_t)s * 832 + d];
    }
#pragma unroll
    for (int j = 0; j < 4; ++j) {
      if (e + j < e1) {
        float l = lg[j] + aDv;
        float lrel = l < 0.f ? 0.2f * l : l;
        lrel = fminf(fmaxf(lrel, -60.f), 40.f);
        float w = __expf(lrel);
        num += w * ms[j];
        den += w;
      }
    }
  }
  return num / den;
}

// k_gat (layers 0..3): writes ONLY xh/xl (xf was dead for these layers).
__global__ __launch_bounds__(256) void k_gat(const float* __restrict__ C,
                                             const int* __restrict__ off,
                                             const int* __restrict__ srcs,
                                             const void* __restrict__ bG,
                                             const int* __restrict__ flg,
                                             int layer,
                                             unsigned short* __restrict__ xh,
                                             unsigned short* __restrict__ xl) {
  int fF = flg[0];
  int idx = blockIdx.x * 256 + threadIdx.x;  // 576*768
  int n = idx / 768, d = idx - n * 768, h = d / 192;
  float g = gelu_exact(gat_aggregate(C, off, srcs, n, d, h) +
                       ldf(bG, (size_t)layer * 768 + d, fF));
  unsigned short hi = f2b(g);
  size_t o = frag_off(n, d);
  xh[o] = hi;
  xl[o] = f2b(g - b2f((unsigned int)hi));
}

// k_gat_last (layer 4): only the 64 text-node rows are consumed by k_final.
// 192 blocks, xf-only output (xh/xl dead after the last layer).
__global__ __launch_bounds__(256) void k_gat_last(const float* __restrict__ C,
                                                  const int* __restrict__ off,
                                                  const int* __restrict__ srcs,
                                                  const void* __restrict__ bG,
                                                  const int* __restrict__ flg,
                                                  float* __restrict__ xf) {
  int fF = flg[0];
  int idx = blockIdx.x * 256 + threadIdx.x;  // 64*768
  int b = idx / 768, d = idx - b * 768, h = d / 192;
  int n = b * 9;  // text node of example b
  float g = gelu_exact(gat_aggregate(C, off, srcs, n, d, h) +
                       ldf(bG, (size_t)4 * 768 + d, fF));
  xf[(size_t)n * 768 + d] = g;
}

// ---------------------------------------------------------------------------
// k_final: round-9 exact (nt stores, 2 rows/wave, hoisted gathers).
// ---------------------------------------------------------------------------
DEV void final_row_f32(int r, int lane, const f32x4* wsrc,
                       const void* seg, const void* typ, const void* post,
                       const void* segt, const void* typt,
                       const void* gamma, const void* beta, int fI,
                       float* __restrict__ outp) {
  int s = r & 511;
  int sg = ldi(seg, (size_t)r, fI), tp = ldi(typ, (size_t)r, fI);
  const f32x4* pr = (const f32x4*)((const float*)post + (size_t)s * 768);
  const f32x4* sr = (const f32x4*)((const float*)segt + (size_t)sg * 768);
  const f32x4* tr = (const f32x4*)((const float*)typt + (size_t)tp * 768);
  float sum = 0.f, sq = 0.f;
  f32x4 vv[3];
#pragma unroll
  for (int j = 0; j < 3; ++j) {
    int p = lane + 64 * j;
    f32x4 a = wsrc[j];
    a += pr[p]; a += sr[p]; a += tr[p];
    vv[j] = a;
#pragma unroll
    for (int c = 0; c < 4; ++c) { sum += a[c]; sq += a[c] * a[c]; }
  }
#pragma unroll
  for (int o = 32; o > 0; o >>= 1) { sum += __shfl_down(sum, o); sq += __shfl_down(sq, o); }
  sum = __shfl(sum, 0); sq = __shfl(sq, 0);
  float mu = sum * (1.f / 768.f);
  float var = fmaxf(sq * (1.f / 768.f) - mu * mu, 0.f);
  float rstd = rsqrtf(var + 1e-6f);
  const f32x4* gm = (const f32x4*)gamma;
  const f32x4* bt = (const f32x4*)beta;
  f32x4* orow = (f32x4*)(outp + (size_t)r * 768);
#pragma unroll
  for (int j = 0; j < 3; ++j) {
    int p = lane + 64 * j;
    f32x4 g4 = gm[p], b4 = bt[p], y;
#pragma unroll
    for (int c = 0; c < 4; ++c) y[c] = g4[c] * (vv[j][c] - mu) * rstd + b4[c];
    __builtin_nontemporal_store(y, &orow[p]);
  }
}

DEV void final_row_bf16(int r, int lane, const void* src, const void* seg,
                        const void* typ, const void* word, const void* post,
                        const void* segt, const void* typt, const void* gamma,
                        const void* beta, const float* xf, int fI,
                        unsigned short* __restrict__ outp) {
  int b = r >> 9, s = r & 511;
  int sg = ldi(seg, (size_t)r, fI), tp = ldi(typ, (size_t)r, fI);
  int wrow = ldi(src, (size_t)r, fI);
  bool cls = (s == 0);
  float sum = 0.f, sq = 0.f;
  float vs[12];
#pragma unroll
  for (int j = 0; j < 12; ++j) {
    int d = lane + 64 * j;
    float xv = cls ? xf[(size_t)b * 6912 + d] : ldf(word, (size_t)wrow * 768 + d, 0);
    xv += ldf(post, (size_t)s * 768 + d, 0);
    xv += ldf(segt, (size_t)sg * 768 + d, 0);
    xv += ldf(typt, (size_t)tp * 768 + d, 0);
    vs[j] = xv;
    sum += xv; sq += xv * xv;
  }
#pragma unroll
  for (int o = 32; o > 0; o >>= 1) { sum += __shfl_down(sum, o); sq += __shfl_down(sq, o); }
  sum = __shfl(sum, 0); sq = __shfl(sq, 0);
  float mu = sum * (1.f / 768.f);
  float var = fmaxf(sq * (1.f / 768.f) - mu * mu, 0.f);
  float rstd = rsqrtf(var + 1e-6f);
#pragma unroll
  for (int j = 0; j < 12; ++j) {
    int d = lane + 64 * j;
    float y = ldf(gamma, (size_t)d, 0) * (vs[j] - mu) * rstd + ldf(beta, (size_t)d, 0);
    outp[(size_t)r * 768 + d] = f2b(y);
  }
}

__global__ __launch_bounds__(256) void k_final(const void* __restrict__ src,
                                               const void* __restrict__ seg,
                                               const void* __restrict__ typ,
                                               const void* __restrict__ word,
                                               const void* __restrict__ post,
                                               const void* __restrict__ segt,
                                               const void* __restrict__ typt,
                                               const void* __restrict__ gamma,
                                               const void* __restrict__ beta,
                                               const float* __restrict__ xf,
                                               const int* __restrict__ flg,
                                               void* __restrict__ out) {
  int fF = flg[0], fI = flg[1];
  int wave = threadIdx.x >> 6, lane = threadIdx.x & 63;
  int r0 = blockIdx.x * 4 + wave, r1 = r0 + 16384;
  if (fF) {
    int s0 = r0 & 511, s1 = r1 & 511;
    int b0 = r0 >> 9, b1 = r1 >> 9;
    int w0r = ldi(src, (size_t)r0, fI), w1r = ldi(src, (size_t)r1, fI);
    const f32x4* p0 = (s0 == 0) ? (const f32x4*)(xf + (size_t)b0 * 6912)
                                : (const f32x4*)((const float*)word + (size_t)w0r * 768);
    const f32x4* p1 = (s1 == 0) ? (const f32x4*)(xf + (size_t)b1 * 6912)
                                : (const f32x4*)((const float*)word + (size_t)w1r * 768);
    f32x4 wa[3], wb[3];
#pragma unroll
    for (int j = 0; j < 3; ++j) { wa[j] = p0[lane + 64 * j]; wb[j] = p1[lane + 64 * j]; }
    final_row_f32(r0, lane, wa, seg, typ, post, segt, typt, gamma, beta, fI, (float*)out);
    final_row_f32(r1, lane, wb, seg, typ, post, segt, typt, gamma, beta, fI, (float*)out);
  } else {
    final_row_bf16(r0, lane, src, seg, typ, word, post, segt, typt, gamma, beta, xf, fI,
                   (unsigned short*)out);
    final_row_bf16(r1, lane, src, seg, typ, word, post, segt, typt, gamma, beta, xf, fI,
                   (unsigned short*)out);
  }
}

extern "C" void kernel_launch(void* const* d_in, const int* in_sizes, int n_in,
                              void* d_out, int out_size, void* d_ws, size_t ws_size,
                              hipStream_t stream) {
  const void* src  = d_in[0];
  const void* seg  = d_in[1];
  const void* typ  = d_in[2];
  const void* pos  = d_in[3];
  const void* sst  = d_in[4];
  const void* sen  = d_in[5];
  const void* edge = d_in[6];
  const void* word = d_in[7];
  const void* post = d_in[8];
  const void* segt = d_in[9];
  const void* typt = d_in[10];
  const void* gamma = d_in[11];
  const void* beta  = d_in[12];
  const void* Wg    = d_in[13];
  const void* aS    = d_in[14];
  const void* aD    = d_in[15];
  const void* bG    = d_in[16];

  char* ws = (char*)d_ws;
  float* xf = (float*)(ws);                               //  1,769,472
  float* C  = (float*)(ws + 1769472);                     //  1,916,928
  unsigned short* xh = (unsigned short*)(ws + 3686400);   //    884,736 (frag-linear)
  unsigned short* xl = (unsigned short*)(ws + 4571136);   //    884,736
  unsigned short* Bh = (unsigned short*)(ws + 5455872);   //  6,389,760 (5 layers, frag-linear)
  unsigned short* Bl = (unsigned short*)(ws + 11845632);  //  6,389,760
  int* csr_off = (int*)(ws + 18358272);                   //      2,320 (pad)
  int* csr_src = (int*)(ws + 18360592);                   //     35,072
  int* flags   = (int*)(ws + 18395664);                   //          8

  k_front<<<dim3(1357), dim3(256), 0, stream>>>(src, sst, sen, edge, word, pos, aS, aD, Wg,
                                                xh, xl, Bh, Bl, csr_off, csr_src, flags);
  for (int l = 0; l < 4; ++l) {
    k_gemm<<<dim3(468), dim3(256), 0, stream>>>(xh, xl,
                                                Bh + (size_t)l * 832 * 768,
                                                Bl + (size_t)l * 832 * 768, C);
    k_gat<<<dim3(1728), dim3(256), 0, stream>>>(C, csr_off, csr_src, bG, flags, l, xh, xl);
  }
  k_gemm<<<dim3(468), dim3(256), 0, stream>>>(xh, xl,
                                              Bh + (size_t)4 * 832 * 768,
                                              Bl + (size_t)4 * 832 * 768, C);
  k_gat_last<<<dim3(192), dim3(256), 0, stream>>>(C, csr_off, csr_src, bG, flags, xf);
  k_final<<<dim3(4096), dim3(256), 0, stream>>>(src, seg, typ, word, post, segt, typt,
                                                gamma, beta, xf, flags, d_out);
}